// Round 6
// baseline (189.694 us; speedup 1.0000x reference)
//
#include <hip/hip_runtime.h>
#include <stdint.h>

#define G_   250
#define P_   200
#define EPG  3200
#define E_   800000
#define F_   128
#define R_   8
#define HROW 136   // f16 elems per row; 272 B stride, 16B-aligned rows
#define NKEY (R_ * P_)   // 1600 (rel,dst) buckets

typedef _Float16 f16x8 __attribute__((ext_vector_type(8)));
typedef _Float16 f16x4 __attribute__((ext_vector_type(4)));
typedef float    f32x4 __attribute__((ext_vector_type(4)));
typedef float    f32x16 __attribute__((ext_vector_type(16)));

// ---------------- prepass: W -> B-fragment layout for mfma_f32_32x32x16_f16 ----------------
// flat = ((((l*9+r)*8 + kt)*4 + ntj)*64 + lane)*8 + j
// value = W[r][k = kt*16 + (lane>>5)*8 + j][n = ntj*32 + (lane&31)]   (r==8 -> root)
__global__ __launch_bounds__(256) void k_wstage(const float* __restrict__ W1, const float* __restrict__ root1,
                                                const float* __restrict__ W2, const float* __restrict__ root2,
                                                _Float16* __restrict__ wf) {
  int t = blockIdx.x * 256 + threadIdx.x;
  if (t >= 2 * 9 * 8 * 4 * 64 * 8) return;
  int j = t & 7;
  int rest = t >> 3;
  int lane = rest & 63; rest >>= 6;
  int ntj = rest & 3;   rest >>= 2;
  int kt = rest & 7;    rest >>= 3;
  int r = rest % 9;
  int l = rest / 9;
  int k = kt * 16 + (lane >> 5) * 8 + j;
  int n = ntj * 32 + (lane & 31);
  const float* Wl = (l == 0) ? W1 : W2;
  const float* rl = (l == 0) ? root1 : root2;
  float v = (r < 8) ? Wl[(r * F_ + k) * F_ + n] : rl[k * F_ + n];
  wf[t] = (_Float16)v;
}

// ---------------- main: one workgroup = one graph; 8 waves x 25-row jobs, 32x32 MFMA ----------
__global__ __launch_bounds__(512, 2) void k_main(
    const float* __restrict__ x, const int* __restrict__ ei, const int* __restrict__ et,
    const _Float16* __restrict__ wf, const float* __restrict__ b1, const float* __restrict__ b2,
    const float* __restrict__ message, const float* __restrict__ embed,
    const float* __restrict__ cw, const float* __restrict__ cb,
    const float* __restrict__ mw, const float* __restrict__ mb,
    float* __restrict__ out) {
  __shared__ __attribute__((aligned(16))) _Float16 hbuf0[P_ * HROW];  // 54400 B (x / layer-1 in)
  __shared__ __attribute__((aligned(16))) _Float16 hbuf1[P_ * HROW];  // 54400 B (h' / layer-2 in)
  __shared__ unsigned short csrS[EPG];                                // 6400 B
  __shared__ int offsS[NKEY + 1];                                     // 6404 B
  __shared__ float msgS[F_ + 1];                                      // 516 B  -> ~122.1 KB

  int g = blockIdx.x, tid = threadIdx.x;
  int lane = tid & 63, wave = tid >> 6;
  int m32 = lane & 31, kh = lane >> 5;

  // ---- setup scratch aliased inside hbuf1 (dead until layer-1 epilogue) ----
  int*   Sint     = (int*)hbuf1;
  int*   cnt      = Sint;                    // [1600]
  int*   cur      = Sint + 1600;             // [1600]
  int*   chunkTot = Sint + 3200;             // [200]
  int*   scanA    = Sint + 3400;             // [256]
  int*   scanB    = Sint + 3656;             // [256]
  float* comb     = (float*)(Sint + 3912);   // [256]
  float* red      = comb + 256;              // [512]
  int*   eRec     = (int*)(red + 512);       // [3200]  => 31.5 KB < 54.4 KB

  // stage x -> hbuf0 (f16)
  for (int i = tid; i < P_ * 32; i += 512) {
    int row = i >> 5, c4 = i & 31;
    const float4 v = ((const float4*)x)[(g * P_ + row) * 32 + c4];
    f16x4 pk = { (_Float16)v.x, (_Float16)v.y, (_Float16)v.z, (_Float16)v.w };
    *((f16x4*)&hbuf0[row * HROW + c4 * 4]) = pk;
  }
  for (int i = tid; i < NKEY; i += 512) { cnt[i] = 0; cur[i] = 0; }
  if (tid < F_) {   // message combined features
    int tok = (int)message[g * 2];
    float cont = message[g * 2 + 1];
    comb[tid] = embed[tok * F_ + tid];
    float ce = cont * cw[tid] + cb[tid];
    comb[F_ + tid] = ce > 0.0f ? ce : 0.0f;
  }
  __syncthreads();
  // edge ingest: pack records into LDS + count buckets
  int base = g * EPG, nbase = g * P_;
  for (int e = tid; e < EPG; e += 512) {
    int s = ei[base + e] - nbase;
    int d = ei[E_ + base + e] - nbase;
    int r = et[base + e];
    eRec[e] = s | (d << 8) | (r << 16);
    atomicAdd(&cnt[r * P_ + d], 1);
  }
  __syncthreads();
  if (tid < 200) {   // per-chunk serial scan (8 buckets each)
    int s = 0;
    for (int i = 0; i < 8; i++) { int c = cnt[tid * 8 + i]; offsS[tid * 8 + i] = s; s += c; }
    chunkTot[tid] = s;
    scanA[tid] = s;
  }
  __syncthreads();
  {  // Hillis-Steele inclusive scan of chunkTot[200]
    int* src = scanA; int* dst = scanB;
    for (int st = 1; st < 256; st <<= 1) {
      if (tid < 200) dst[tid] = src[tid] + (tid >= st ? src[tid - st] : 0);
      __syncthreads();
      int* tmp = src; src = dst; dst = tmp;
    }
  }
  if (tid < 200) {
    int add = scanA[tid] - chunkTot[tid];   // exclusive chunk base
    for (int i = 0; i < 8; i++) offsS[tid * 8 + i] += add;
  }
  if (tid == 0) offsS[NKEY] = EPG;
  {   // message matmul partials: 4 segs x 128 cols
    int col = tid & 127, seg = tid >> 7;
    float acc = 0.0f;
#pragma unroll 8
    for (int k = seg * 64; k < seg * 64 + 64; k++) acc += comb[k] * mw[k * F_ + col];
    red[tid] = acc;
  }
  __syncthreads();
  // CSR scatter from LDS records
  for (int e = tid; e < EPG; e += 512) {
    int rec = eRec[e];
    int s = rec & 255, d = (rec >> 8) & 255, r = rec >> 16;
    int key = r * P_ + d;
    int pos = atomicAdd(&cur[key], 1);
    csrS[offsS[key] + pos] = (unsigned short)s;
  }
  if (tid < F_) {
    float a = mb[tid] + red[tid] + red[128 + tid] + red[256 + tid] + red[384 + tid];
    a = a > 0.0f ? a : 0.0f;
    msgS[tid] = a;
    comb[tid] = a * b2[tid];   // for db2 = dot(msg, b2)
  }
  __syncthreads();
  if (tid < 64) comb[tid] += comb[tid + 64];
  __syncthreads();
  if (tid < 32) comb[tid] += comb[tid + 32];
  __syncthreads();
  if (tid < 16) comb[tid] += comb[tid + 16];
  __syncthreads();
  if (tid == 0) {
    float s = 0.0f;
    for (int i = 0; i < 16; i++) s += comb[i];
    msgS[F_] = s;
  }
  __syncthreads();   // hbuf0 + csr + offs + msg ready; hbuf1 scratch dead

  // ---- fused layers: wave w owns rows [w*25, w*25+25); no barriers except between layers ----
  int jobBase = wave * 25;
  bool rowAct = (m32 < 25);
  int myD = jobBase + m32;                 // this lane's dst row (valid if rowAct)
  int ck = kh * 8;                         // k-col base within 16-chunk

  for (int l = 0; l < 2; l++) {
    const _Float16* Ap = (l == 0) ? hbuf0 : hbuf1;
    f32x16 acc[4];
#pragma unroll
    for (int nt = 0; nt < 4; nt++)
#pragma unroll
      for (int i = 0; i < 16; i++) acc[nt][i] = 0.0f;
    const _Float16* wl = wf + l * (9 * 8 * 4 * 64 * 8);
    for (int r = 0; r < 9; r++) {
      // prefetch ALL B-fragments for this relation (32 x 16 B, L2) -> fly during gather
      f16x8 Bf[8][4];
      const _Float16* wr = wl + r * (8 * 4 * 64 * 8);
#pragma unroll
      for (int kt = 0; kt < 8; kt++)
#pragma unroll
        for (int nt = 0; nt < 4; nt++)
          Bf[kt][nt] = *((const f16x8*)(wr + ((kt * 4 + nt) * 64 + lane) * 8));
      f16x8 a[8];
      if (r < 8) {
        int o = 0, n = 0;
        if (rowAct) { int key = r * P_ + myD; o = offsS[key]; n = offsS[key + 1] - o; }
        f16x8 z = {0, 0, 0, 0, 0, 0, 0, 0};
#pragma unroll
        for (int kt = 0; kt < 8; kt++) a[kt] = z;
        int sNext = (n > 0) ? (int)csrS[o] : 0;
        for (int t = 0; t < n; t++) {
          int sc = sNext;
          if (t + 1 < n) sNext = (int)csrS[o + t + 1];
          const _Float16* hp = &Ap[sc * HROW + ck];
#pragma unroll
          for (int kt = 0; kt < 8; kt++) a[kt] += *((const f16x8*)(hp + kt * 16));
        }
        float nf = (n > 0) ? 1.0f / (float)n : 0.0f;
        _Float16 nh = (_Float16)nf;
#pragma unroll
        for (int kt = 0; kt < 8; kt++) a[kt] *= nh;
      } else {
        int rowA = jobBase + (rowAct ? m32 : 24);
        const _Float16* hp = &Ap[rowA * HROW + ck];
#pragma unroll
        for (int kt = 0; kt < 8; kt++) a[kt] = *((const f16x8*)(hp + kt * 16));
      }
#pragma unroll
      for (int kt = 0; kt < 8; kt++)
#pragma unroll
        for (int nt = 0; nt < 4; nt++)
          acc[nt] = __builtin_amdgcn_mfma_f32_32x32x16_f16(a[kt], Bf[kt][nt], acc[nt], 0, 0, 0);
    }
    if (l == 0) {
      // h' = relu(acc + b1) -> hbuf1; C layout: col=lane&31, row=(reg&3)+8*(reg>>2)+4*kh
#pragma unroll
      for (int nt = 0; nt < 4; nt++) {
        int col = nt * 32 + m32;
        float bias = b1[col];
#pragma unroll
        for (int reg = 0; reg < 16; reg++) {
          int row = (reg & 3) + 8 * (reg >> 2) + 4 * kh;
          if (row < 25) {
            float v = acc[nt][reg] + bias;
            v = v > 0.0f ? v : 0.0f;
            hbuf1[(jobBase + row) * HROW + col] = (_Float16)v;
          }
        }
      }
      __syncthreads();   // h' complete before layer-2 gathers
    } else {
      // score = dot(node_emb, msg) + dot(b2, msg); reduce over 32 col-lanes per half
      float db2 = msgS[F_];
#pragma unroll
      for (int reg = 0; reg < 16; reg++) {
        int row = (reg & 3) + 8 * (reg >> 2) + 4 * kh;
        float p = 0.0f;
#pragma unroll
        for (int nt = 0; nt < 4; nt++)
          p += acc[nt][reg] * msgS[nt * 32 + m32];
        p += __shfl_xor(p, 16, 32);
        p += __shfl_xor(p, 8, 32);
        p += __shfl_xor(p, 4, 32);
        p += __shfl_xor(p, 2, 32);
        p += __shfl_xor(p, 1, 32);
        if (m32 == 0 && row < 25)
          out[g * P_ + jobBase + row] = p + db2;
      }
    }
  }
}

extern "C" void kernel_launch(void* const* d_in, const int* in_sizes, int n_in,
                              void* d_out, int out_size, void* d_ws, size_t ws_size,
                              hipStream_t stream) {
  const float* message = (const float*)d_in[0];
  const float* x       = (const float*)d_in[1];
  const int*   ei      = (const int*)d_in[2];
  const int*   et      = (const int*)d_in[3];
  const float* W1      = (const float*)d_in[6];
  const float* root1   = (const float*)d_in[7];
  const float* b1      = (const float*)d_in[8];
  const float* W2      = (const float*)d_in[9];
  const float* root2   = (const float*)d_in[10];
  const float* b2      = (const float*)d_in[11];
  const float* embed   = (const float*)d_in[12];
  const float* cw      = (const float*)d_in[13];
  const float* cb      = (const float*)d_in[14];
  const float* mw      = (const float*)d_in[15];
  const float* mb      = (const float*)d_in[16];

  _Float16* wfrag = (_Float16*)d_ws;   // 589,824 B
  float*    out   = (float*)d_out;

  hipLaunchKernelGGL(k_wstage, dim3(1152), dim3(256), 0, stream, W1, root1, W2, root2, wfrag);
  hipLaunchKernelGGL(k_main, dim3(G_), dim3(512), 0, stream, x, ei, et, wfrag, b1, b2,
                     message, embed, cw, cb, mw, mb, out);
}